// Round 7
// baseline (301.559 us; speedup 1.0000x reference)
//
#include <hip/hip_runtime.h>
#include <hip/hip_fp16.h>

#ifndef MIN
#define MIN(a,b) ((a)<(b)?(a):(b))
#endif

// Bucketing: bucket = dst >> BSHIFT, 512 nodes/bucket, K = ceil(N/512) <= 256.
#define BSHIFT 9
#define NB1 256          // blocks in histogram pass
#define TILE 4096        // edges per B3 block
#define B4CAP 12288      // LDS adj capacity per bucket (avg ~8163, max ~8600)

typedef float floatx2 __attribute__((ext_vector_type(2)));

#if defined(__has_builtin)
#if __has_builtin(__builtin_amdgcn_cvt_pk_f32_fp8) && __has_builtin(__builtin_amdgcn_cvt_pk_fp8_f32)
#define HW_FP8 1
#endif
#endif

// ---- fp8 e4m3 (OCP) pair decode/encode; HW path on gfx950 ----
// HI selects low/high 16 bits of the word; must be a compile-time constant
// for the builtin, hence the template parameter.
template <bool HI>
__device__ __forceinline__ floatx2 fp8x2_dec_word(unsigned w) {
#ifdef HW_FP8
    return __builtin_amdgcn_cvt_pk_f32_fp8((int)w, HI);
#else
    unsigned v = HI ? (w >> 16) : w;
    floatx2 r;
    unsigned b0 = v & 0xFFu, b1 = (v >> 8) & 0xFFu;
    float f0 = __uint_as_float(((b0 & 0x80u) << 24) | ((b0 & 0x7Fu) << 20));
    float f1 = __uint_as_float(((b1 & 0x80u) << 24) | ((b1 & 0x7Fu) << 20));
    r.x = f0 * 1.329227995784916e+36f;   // 2^120
    r.y = f1 * 1.329227995784916e+36f;
    return r;
#endif
}

__device__ __forceinline__ unsigned short fp8x2_enc(float x, float y) {
#ifdef HW_FP8
    int p = __builtin_amdgcn_cvt_pk_fp8_f32(x, y, 0, false);
    return (unsigned short)((unsigned)p & 0xFFFFu);
#else
    auto enc1 = [](float f) -> unsigned {
        float yv = f * 7.52316384526264e-37f;   // 2^-120
        unsigned u = __float_as_uint(yv);
        unsigned s = (u >> 24) & 0x80u;
        unsigned em = u & 0x7FFFFFFFu;
        unsigned keep = em >> 20;
        unsigned rem = em & 0xFFFFFu;
        keep += (rem > 0x80000u || (rem == 0x80000u && (keep & 1u))) ? 1u : 0u;
        if (keep > 0x7Fu) keep = 0x7Fu;
        return s | keep;
    };
    return (unsigned short)(enc1(x) | (enc1(y) << 8));
#endif
}

// ---------------- B1: per-block bucket histogram (LDS, no global atomics) ---
__global__ void __launch_bounds__(256) k_hist(const int* __restrict__ dst, int E,
                                              unsigned* __restrict__ partial) {
    __shared__ unsigned c[256];
    int t = threadIdx.x;
    c[t] = 0;
    __syncthreads();
    int i = blockIdx.x * blockDim.x + t;
    int stride = gridDim.x * blockDim.x;
    for (; i < E; i += stride) atomicAdd(&c[((unsigned)dst[i]) >> BSHIFT], 1);
    __syncthreads();
    partial[blockIdx.x * 256 + t] = c[t];
}

// ---------------- B2: reduce partials, scan -> bucket bases/cursors ---------
__global__ void __launch_bounds__(256) k_bscan(const unsigned* __restrict__ partial,
                                               int K, unsigned* __restrict__ bcnt,
                                               unsigned* __restrict__ bbase,
                                               unsigned* __restrict__ gcur,
                                               int* __restrict__ offs, int N, int E) {
    __shared__ unsigned sm[256];
    int t = threadIdx.x;
    unsigned s = 0;
    if (t < K)
        for (int blk = 0; blk < NB1; ++blk) s += partial[blk * 256 + t];
    sm[t] = (t < K) ? s : 0;
    __syncthreads();
    unsigned v = sm[t];
    for (int off = 1; off < 256; off <<= 1) {
        unsigned x = (t >= off) ? sm[t - off] : 0;
        __syncthreads();
        sm[t] += x;
        __syncthreads();
    }
    unsigned excl = sm[t] - v;
    if (t < K) {
        bcnt[t] = s;
        bbase[t] = excl;
        gcur[t] = excl;
    }
    if (t == 0) offs[N] = E;
}

// ---------------- B3: multisplit — tile-local sort by bucket, coalesced out -
__global__ void __launch_bounds__(256) k_split(const int* __restrict__ src,
                                               const int* __restrict__ dst, int E,
                                               unsigned* __restrict__ gcur,
                                               uint2* __restrict__ pairs) {
    __shared__ uint2 sp[TILE];            // 32 KB
    __shared__ unsigned cnt[256], sscan[256], gb[256];
    int t = threadIdx.x;
    int base = blockIdx.x * TILE;
    cnt[t] = 0;
    __syncthreads();

    unsigned pk[TILE / 256];
    #pragma unroll
    for (int j = 0; j < TILE / 256; ++j) {
        int i = base + j * 256 + t;
        if (i < E) {
            unsigned b = ((unsigned)dst[i]) >> BSHIFT;
            unsigned r = atomicAdd(&cnt[b], 1);
            pk[j] = (b << 16) | r;        // r < 4096, b < 256
        } else {
            pk[j] = 0xFFFFFFFFu;
        }
    }
    __syncthreads();

    // exclusive scan of cnt -> sscan
    unsigned v = cnt[t];
    sscan[t] = v;
    __syncthreads();
    for (int off = 1; off < 256; off <<= 1) {
        unsigned x = (t >= off) ? sscan[t - off] : 0;
        __syncthreads();
        sscan[t] += x;
        __syncthreads();
    }
    sscan[t] -= v;
    __syncthreads();

    // local scatter into bucket-sorted order
    #pragma unroll
    for (int j = 0; j < TILE / 256; ++j) {
        if (pk[j] != 0xFFFFFFFFu) {
            int i = base + j * 256 + t;
            unsigned b = pk[j] >> 16, r = pk[j] & 0xFFFFu;
            sp[sscan[b] + r] = make_uint2((unsigned)src[i], (unsigned)dst[i]);
        }
    }
    __syncthreads();

    // one global claim per non-empty bucket
    unsigned n = cnt[t];
    gb[t] = n ? atomicAdd(&gcur[t], n) : 0u;
    __syncthreads();

    // coalesced write-out in bucket-run order
    int cntTile = MIN(TILE, E - base);
    #pragma unroll
    for (int j = 0; j < TILE / 256; ++j) {
        int p = j * 256 + t;
        if (p < cntTile) {
            uint2 e = sp[p];
            unsigned b = e.y >> BSHIFT;
            pairs[gb[b] + (unsigned)p - sscan[b]] = e;
        }
    }
}

// ---------------- B4: per-bucket CSR build fully in LDS, coalesced out ------
__global__ void __launch_bounds__(512) k_csr(const uint2* __restrict__ pairs,
                                             const unsigned* __restrict__ bcnt,
                                             const unsigned* __restrict__ bbase,
                                             int* __restrict__ adj,
                                             int* __restrict__ offs, int N) {
    __shared__ unsigned adjL[B4CAP];      // 48 KB
    __shared__ unsigned cnt[512], cnt2[512], sc[512];
    int t = threadIdx.x;
    int b = blockIdx.x;
    unsigned nb = bcnt[b];
    unsigned bb = bbase[b];
    cnt[t] = 0;
    cnt2[t] = 0;
    __syncthreads();

    for (unsigned i = t; i < nb; i += 512)
        atomicAdd(&cnt[pairs[bb + i].y & 511u], 1);
    __syncthreads();

    // exclusive scan of per-node counts
    unsigned v = cnt[t];
    sc[t] = v;
    __syncthreads();
    for (int off = 1; off < 512; off <<= 1) {
        unsigned x = (t >= off) ? sc[t - off] : 0;
        __syncthreads();
        sc[t] += x;
        __syncthreads();
    }
    sc[t] -= v;
    __syncthreads();

    int node = (b << BSHIFT) + t;
    if (node < N) offs[node] = (int)(bb + sc[t]);

    if (nb <= B4CAP) {
        for (unsigned i = t; i < nb; i += 512) {
            uint2 e = pairs[bb + i];
            unsigned dl = e.y & 511u;
            unsigned pos = sc[dl] + atomicAdd(&cnt2[dl], 1);
            adjL[pos] = e.x;
        }
        __syncthreads();
        for (unsigned i = t; i < nb; i += 512) adj[bb + i] = (int)adjL[i];
    } else {  // statistical impossibility fallback, kept for safety
        for (unsigned i = t; i < nb; i += 512) {
            uint2 e = pairs[bb + i];
            unsigned dl = e.y & 511u;
            unsigned pos = sc[dl] + atomicAdd(&cnt2[dl], 1);
            adj[bb + pos] = (int)e.x;
        }
    }
}

// ---------------- layer 0: copy x -> out (f32) and build fp8 gather table ---
__global__ void k_init(const float2* __restrict__ x2, float2* __restrict__ out2,
                       unsigned short* __restrict__ t8, int n2) {
    int i = blockIdx.x * blockDim.x + threadIdx.x;
    int stride = gridDim.x * blockDim.x;
    for (; i < n2; i += stride) {
        float2 v = x2[i];
        out2[i] = v;
        t8[i] = fp8x2_enc(v.x, v.y);
    }
}

// ---------------- aggregation layer: one wave per node, 4 edges/instruction -
// fp8 table row = 128 B = 16 uint2. Lane l: grp = l>>4 (edge within quad),
// slot = l&15 (8 features as uint2). One dwordx2 gather covers 4 edges ->
// 4x fewer vmem instructions (TA-bound fix). f32 accumulate in acc[8];
// butterfly over lane-groups (xor 16,32) at node end.
__global__ void __launch_bounds__(256) k_layer(
        const unsigned short* __restrict__ hin, float2* __restrict__ hout,
        unsigned short* __restrict__ tout, const int* __restrict__ adj,
        const int* __restrict__ offs, int N) {
    int wave = (blockIdx.x * blockDim.x + threadIdx.x) >> 6;
    int lane = threadIdx.x & 63;
    if (wave >= N) return;
    const int node = wave;
    const int beg = offs[node];
    const int end = offs[node + 1];
    const int grp = lane >> 4;         // 0..3
    const int slot = lane & 15;        // 0..15

    const uint2* __restrict__ tab = (const uint2*)hin;   // row = 16 uint2

    float acc[8];
    #pragma unroll
    for (int k = 0; k < 8; ++k) acc[k] = 0.f;

    auto accum = [&](uint2 v) {
        floatx2 f0 = fp8x2_dec_word<false>(v.x);
        floatx2 f1 = fp8x2_dec_word<true>(v.x);
        floatx2 f2 = fp8x2_dec_word<false>(v.y);
        floatx2 f3 = fp8x2_dec_word<true>(v.y);
        acc[0] += f0.x; acc[1] += f0.y;
        acc[2] += f1.x; acc[3] += f1.y;
        acc[4] += f2.x; acc[5] += f2.y;
        acc[6] += f3.x; acc[7] += f3.y;
    };

    int e = beg;
    // main loop: 16 edges per iteration = 4 dwordx2 gathers in flight per lane
    for (; e + 16 <= end; e += 16) {
        int s0 = adj[e + grp];
        int s1 = adj[e + 4 + grp];
        int s2 = adj[e + 8 + grp];
        int s3 = adj[e + 12 + grp];
        uint2 v0 = tab[(size_t)s0 * 16 + slot];
        uint2 v1 = tab[(size_t)s1 * 16 + slot];
        uint2 v2 = tab[(size_t)s2 * 16 + slot];
        uint2 v3 = tab[(size_t)s3 * 16 + slot];
        accum(v0); accum(v1); accum(v2); accum(v3);
    }
    for (; e + 4 <= end; e += 4) {
        int s = adj[e + grp];
        uint2 v = tab[(size_t)s * 16 + slot];
        accum(v);
    }
    {
        int r = end - e;               // 0..3 leftover edges
        if (grp < r) {
            int s = adj[e + grp];
            uint2 v = tab[(size_t)s * 16 + slot];
            accum(v);
        }
    }

    // reduce across the 4 lane-groups (lanes differing in bits 4,5)
    #pragma unroll
    for (int k = 0; k < 8; ++k) {
        acc[k] += __shfl_xor(acc[k], 16);
        acc[k] += __shfl_xor(acc[k], 32);
    }

    // self-loop: every lane adds its slot of the node's own row (groups stay
    // identical since all read the same 8 B)
    {
        uint2 sv = tab[(size_t)node * 16 + slot];
        floatx2 f0 = fp8x2_dec_word<false>(sv.x);
        floatx2 f1 = fp8x2_dec_word<true>(sv.x);
        floatx2 f2 = fp8x2_dec_word<false>(sv.y);
        floatx2 f3 = fp8x2_dec_word<true>(sv.y);
        acc[0] += f0.x; acc[1] += f0.y;
        acc[2] += f1.x; acc[3] += f1.y;
        acc[4] += f2.x; acc[5] += f2.y;
        acc[6] += f3.x; acc[7] += f3.y;
    }

    const float w = 1.0f / (float)(end - beg + 1);    // 1/(deg+1)
    #pragma unroll
    for (int k = 0; k < 8; ++k) acc[k] *= w;

    // f32 output: lane l writes features [slot*8 + grp*2, +1] -> float2 index
    // slot*4 + grp; full wave covers the 512 B row exactly once (coalesced).
    float2 r2;
    r2.x = acc[grp * 2];
    r2.y = acc[grp * 2 + 1];
    hout[(size_t)node * 64 + slot * 4 + grp] = r2;

    // fp8 table for next layer: grp-0 lanes write 8 B each (16 x 8 B = 128 B)
    if (tout && grp == 0) {
        uint2 p;
        p.x = (unsigned)fp8x2_enc(acc[0], acc[1]) |
              ((unsigned)fp8x2_enc(acc[2], acc[3]) << 16);
        p.y = (unsigned)fp8x2_enc(acc[4], acc[5]) |
              ((unsigned)fp8x2_enc(acc[6], acc[7]) << 16);
        ((uint2*)tout)[(size_t)node * 16 + slot] = p;
    }
}

extern "C" void kernel_launch(void* const* d_in, const int* in_sizes, int n_in,
                              void* d_out, int out_size, void* d_ws, size_t ws_size,
                              hipStream_t stream) {
    const float* x = (const float*)d_in[0];
    const int* ei = (const int*)d_in[1];
    const int N = in_sizes[0] / 128;   // D = 128
    const int E = in_sizes[1] / 2;
    const int* src = ei;
    const int* dst = ei + E;
    float* out = (float*)d_out;
    const int K = (N + 511) >> BSHIFT; // buckets (196 for N=100000)

    // workspace carve-out (256B aligned)
    char* ws = (char*)d_ws;
    size_t off = 0;
    auto carve = [&](size_t bytes) {
        void* p = ws + off;
        off = (off + bytes + 255) & ~(size_t)255;
        return p;
    };
    unsigned* partial = (unsigned*)carve((size_t)NB1 * 256 * 4);
    unsigned* bcnt    = (unsigned*)carve(256 * 4);
    unsigned* bbase   = (unsigned*)carve(256 * 4);
    unsigned* gcur    = (unsigned*)carve(256 * 4);
    int*      offs    = (int*)carve(((size_t)N + 1) * 4);
    uint2*    pairs   = (uint2*)carve((size_t)E * 8);
    int*      adj     = (int*)carve((size_t)E * 4);
    unsigned short* tab0 = (unsigned short*)carve((size_t)N * 64 * 2);  // fp8 ping
    unsigned short* tab1 = (unsigned short*)carve((size_t)N * 64 * 2);  // fp8 pong

    k_hist<<<NB1, 256, 0, stream>>>(dst, E, partial);
    k_bscan<<<1, 256, 0, stream>>>(partial, K, bcnt, bbase, gcur, offs, N, E);
    k_split<<<(E + TILE - 1) / TILE, 256, 0, stream>>>(src, dst, E, gcur, pairs);
    k_csr<<<K, 512, 0, stream>>>(pairs, bcnt, bbase, adj, offs, N);

    const int n2 = N * 64;   // ushort / float2 elements per layer
    k_init<<<MIN((n2 + 255) / 256, 2048), 256, 0, stream>>>(
        (const float2*)x, (float2*)out, tab0, n2);

    const size_t layer_sz = (size_t)N * 128;
    unsigned short* tabs[2] = { tab0, tab1 };
    for (int l = 1; l <= 3; ++l) {
        float* hout = out + (size_t)l * layer_sz;
        unsigned short* tin = tabs[(l - 1) & 1];
        unsigned short* tnext = (l < 3) ? tabs[l & 1] : (unsigned short*)nullptr;
        k_layer<<<(N + 3) / 4, 256, 0, stream>>>(tin, (float2*)hout, tnext, adj, offs, N);
    }
}

// Round 8
// 205.517 us; speedup vs baseline: 1.4673x; 1.4673x over previous
//
#include <hip/hip_runtime.h>
#include <hip/hip_fp16.h>

#ifndef MIN
#define MIN(a,b) ((a)<(b)?(a):(b))
#endif

// Bucketing: bucket = dst >> BSHIFT, 512 nodes/bucket, K = ceil(N/512) <= 256.
#define BSHIFT 9
#define NB1 256          // blocks in histogram pass
#define TILE 4096        // edges per B3 block
#define B4CAP 12288      // LDS adj capacity per bucket (avg ~8163, max ~8600)

typedef float floatx2 __attribute__((ext_vector_type(2)));

#if defined(__has_builtin)
#if __has_builtin(__builtin_amdgcn_cvt_pk_f32_fp8) && __has_builtin(__builtin_amdgcn_cvt_pk_fp8_f32)
#define HW_FP8 1
#endif
#endif

// ---- fp8 e4m3 (OCP) pair decode/encode; HW path on gfx950 ----
// HI must be a compile-time constant for the builtin.
template <bool HI>
__device__ __forceinline__ floatx2 fp8x2_dec_word(unsigned w) {
#ifdef HW_FP8
    return __builtin_amdgcn_cvt_pk_f32_fp8((int)w, HI);
#else
    unsigned v = HI ? (w >> 16) : w;
    floatx2 r;
    unsigned b0 = v & 0xFFu, b1 = (v >> 8) & 0xFFu;
    float f0 = __uint_as_float(((b0 & 0x80u) << 24) | ((b0 & 0x7Fu) << 20));
    float f1 = __uint_as_float(((b1 & 0x80u) << 24) | ((b1 & 0x7Fu) << 20));
    r.x = f0 * 1.329227995784916e+36f;   // 2^120
    r.y = f1 * 1.329227995784916e+36f;
    return r;
#endif
}

__device__ __forceinline__ unsigned short fp8x2_enc(float x, float y) {
#ifdef HW_FP8
    int p = __builtin_amdgcn_cvt_pk_fp8_f32(x, y, 0, false);
    return (unsigned short)((unsigned)p & 0xFFFFu);
#else
    auto enc1 = [](float f) -> unsigned {
        float yv = f * 7.52316384526264e-37f;   // 2^-120
        unsigned u = __float_as_uint(yv);
        unsigned s = (u >> 24) & 0x80u;
        unsigned em = u & 0x7FFFFFFFu;
        unsigned keep = em >> 20;
        unsigned rem = em & 0xFFFFFu;
        keep += (rem > 0x80000u || (rem == 0x80000u && (keep & 1u))) ? 1u : 0u;
        if (keep > 0x7Fu) keep = 0x7Fu;
        return s | keep;
    };
    return (unsigned short)(enc1(x) | (enc1(y) << 8));
#endif
}

// ---------------- B1: per-block bucket histogram (LDS, no global atomics) ---
__global__ void __launch_bounds__(256) k_hist(const int* __restrict__ dst, int E,
                                              unsigned* __restrict__ partial) {
    __shared__ unsigned c[256];
    int t = threadIdx.x;
    c[t] = 0;
    __syncthreads();
    int i = blockIdx.x * blockDim.x + t;
    int stride = gridDim.x * blockDim.x;
    for (; i < E; i += stride) atomicAdd(&c[((unsigned)dst[i]) >> BSHIFT], 1);
    __syncthreads();
    partial[blockIdx.x * 256 + t] = c[t];
}

// ---------------- B2: reduce partials, scan -> bucket bases/cursors ---------
__global__ void __launch_bounds__(256) k_bscan(const unsigned* __restrict__ partial,
                                               int K, unsigned* __restrict__ bcnt,
                                               unsigned* __restrict__ bbase,
                                               unsigned* __restrict__ gcur,
                                               int* __restrict__ offs, int N, int E) {
    __shared__ unsigned sm[256];
    int t = threadIdx.x;
    unsigned s = 0;
    if (t < K)
        for (int blk = 0; blk < NB1; ++blk) s += partial[blk * 256 + t];
    sm[t] = (t < K) ? s : 0;
    __syncthreads();
    unsigned v = sm[t];
    for (int off = 1; off < 256; off <<= 1) {
        unsigned x = (t >= off) ? sm[t - off] : 0;
        __syncthreads();
        sm[t] += x;
        __syncthreads();
    }
    unsigned excl = sm[t] - v;
    if (t < K) {
        bcnt[t] = s;
        bbase[t] = excl;
        gcur[t] = excl;
    }
    if (t == 0) offs[N] = E;
}

// ---------------- B3: multisplit — tile-local sort by bucket, coalesced out -
__global__ void __launch_bounds__(256) k_split(const int* __restrict__ src,
                                               const int* __restrict__ dst, int E,
                                               unsigned* __restrict__ gcur,
                                               uint2* __restrict__ pairs) {
    __shared__ uint2 sp[TILE];            // 32 KB
    __shared__ unsigned cnt[256], sscan[256], gb[256];
    int t = threadIdx.x;
    int base = blockIdx.x * TILE;
    cnt[t] = 0;
    __syncthreads();

    unsigned pk[TILE / 256];
    #pragma unroll
    for (int j = 0; j < TILE / 256; ++j) {
        int i = base + j * 256 + t;
        if (i < E) {
            unsigned b = ((unsigned)dst[i]) >> BSHIFT;
            unsigned r = atomicAdd(&cnt[b], 1);
            pk[j] = (b << 16) | r;        // r < 4096, b < 256
        } else {
            pk[j] = 0xFFFFFFFFu;
        }
    }
    __syncthreads();

    // exclusive scan of cnt -> sscan
    unsigned v = cnt[t];
    sscan[t] = v;
    __syncthreads();
    for (int off = 1; off < 256; off <<= 1) {
        unsigned x = (t >= off) ? sscan[t - off] : 0;
        __syncthreads();
        sscan[t] += x;
        __syncthreads();
    }
    sscan[t] -= v;
    __syncthreads();

    // local scatter into bucket-sorted order
    #pragma unroll
    for (int j = 0; j < TILE / 256; ++j) {
        if (pk[j] != 0xFFFFFFFFu) {
            int i = base + j * 256 + t;
            unsigned b = pk[j] >> 16, r = pk[j] & 0xFFFFu;
            sp[sscan[b] + r] = make_uint2((unsigned)src[i], (unsigned)dst[i]);
        }
    }
    __syncthreads();

    // one global claim per non-empty bucket
    unsigned n = cnt[t];
    gb[t] = n ? atomicAdd(&gcur[t], n) : 0u;
    __syncthreads();

    // coalesced write-out in bucket-run order
    int cntTile = MIN(TILE, E - base);
    #pragma unroll
    for (int j = 0; j < TILE / 256; ++j) {
        int p = j * 256 + t;
        if (p < cntTile) {
            uint2 e = sp[p];
            unsigned b = e.y >> BSHIFT;
            pairs[gb[b] + (unsigned)p - sscan[b]] = e;
        }
    }
}

// ---------------- B4: per-bucket CSR build fully in LDS, coalesced out ------
__global__ void __launch_bounds__(512) k_csr(const uint2* __restrict__ pairs,
                                             const unsigned* __restrict__ bcnt,
                                             const unsigned* __restrict__ bbase,
                                             int* __restrict__ adj,
                                             int* __restrict__ offs, int N) {
    __shared__ unsigned adjL[B4CAP];      // 48 KB
    __shared__ unsigned cnt[512], cnt2[512], sc[512];
    int t = threadIdx.x;
    int b = blockIdx.x;
    unsigned nb = bcnt[b];
    unsigned bb = bbase[b];
    cnt[t] = 0;
    cnt2[t] = 0;
    __syncthreads();

    for (unsigned i = t; i < nb; i += 512)
        atomicAdd(&cnt[pairs[bb + i].y & 511u], 1);
    __syncthreads();

    // exclusive scan of per-node counts
    unsigned v = cnt[t];
    sc[t] = v;
    __syncthreads();
    for (int off = 1; off < 512; off <<= 1) {
        unsigned x = (t >= off) ? sc[t - off] : 0;
        __syncthreads();
        sc[t] += x;
        __syncthreads();
    }
    sc[t] -= v;
    __syncthreads();

    int node = (b << BSHIFT) + t;
    if (node < N) offs[node] = (int)(bb + sc[t]);

    if (nb <= B4CAP) {
        for (unsigned i = t; i < nb; i += 512) {
            uint2 e = pairs[bb + i];
            unsigned dl = e.y & 511u;
            unsigned pos = sc[dl] + atomicAdd(&cnt2[dl], 1);
            adjL[pos] = e.x;
        }
        __syncthreads();
        for (unsigned i = t; i < nb; i += 512) adj[bb + i] = (int)adjL[i];
    } else {  // statistical impossibility fallback, kept for safety
        for (unsigned i = t; i < nb; i += 512) {
            uint2 e = pairs[bb + i];
            unsigned dl = e.y & 511u;
            unsigned pos = sc[dl] + atomicAdd(&cnt2[dl], 1);
            adj[bb + pos] = (int)e.x;
        }
    }
}

// ---------------- layer 0: copy x -> out (f32) and build fp8 gather table ---
__global__ void k_init(const float2* __restrict__ x2, float2* __restrict__ out2,
                       unsigned short* __restrict__ t8, int n2) {
    int i = blockIdx.x * blockDim.x + threadIdx.x;
    int stride = gridDim.x * blockDim.x;
    for (; i < n2; i += stride) {
        float2 v = x2[i];
        out2[i] = v;
        t8[i] = fp8x2_enc(v.x, v.y);
    }
}

// ---------------- aggregation layer: one wave per node, fp8 row gathers -----
// Round-5 shape (one 128 B row per gather instruction, 2 B/lane) + scalar
// adjacency: node/edge indices are pushed through readfirstlane so offs/adj
// loads become provably wave-uniform -> s_load via the scalar cache (lgkmcnt),
// halving the TA/vmem instruction stream (1 vmem gather per edge).
__global__ void __launch_bounds__(256) k_layer(
        const unsigned short* __restrict__ hin, float2* __restrict__ hout,
        unsigned short* __restrict__ tout, const int* __restrict__ adj,
        const int* __restrict__ offs, int N) {
    int wave = (blockIdx.x * blockDim.x + threadIdx.x) >> 6;
    int lane = threadIdx.x & 63;
    if (wave >= N) return;
    const int node = __builtin_amdgcn_readfirstlane(wave);
    const int beg = offs[node];
    const int end = offs[node + 1];

    floatx2 sf = fp8x2_dec_word<false>((unsigned)hin[(size_t)node * 64 + lane]);
    float ax = sf.x, ay = sf.y;          // self (self-loop)
    float bx = 0.f, by = 0.f;

    int e = beg;
    for (; e + 16 <= end; e += 16) {
        const int* __restrict__ a = adj + __builtin_amdgcn_readfirstlane(e);
        int s[16];
        #pragma unroll
        for (int j = 0; j < 16; ++j) s[j] = a[j];
        unsigned short v[16];
        #pragma unroll
        for (int j = 0; j < 16; ++j) v[j] = hin[(size_t)s[j] * 64 + lane];
        #pragma unroll
        for (int j = 0; j < 16; j += 2) {
            floatx2 f0 = fp8x2_dec_word<false>((unsigned)v[j]);
            floatx2 f1 = fp8x2_dec_word<false>((unsigned)v[j + 1]);
            ax += f0.x; ay += f0.y;
            bx += f1.x; by += f1.y;
        }
    }
    for (; e + 8 <= end; e += 8) {
        const int* __restrict__ a = adj + __builtin_amdgcn_readfirstlane(e);
        int s[8];
        #pragma unroll
        for (int j = 0; j < 8; ++j) s[j] = a[j];
        unsigned short v[8];
        #pragma unroll
        for (int j = 0; j < 8; ++j) v[j] = hin[(size_t)s[j] * 64 + lane];
        #pragma unroll
        for (int j = 0; j < 8; j += 2) {
            floatx2 f0 = fp8x2_dec_word<false>((unsigned)v[j]);
            floatx2 f1 = fp8x2_dec_word<false>((unsigned)v[j + 1]);
            ax += f0.x; ay += f0.y;
            bx += f1.x; by += f1.y;
        }
    }
    for (; e + 2 <= end; e += 2) {
        const int* __restrict__ a = adj + __builtin_amdgcn_readfirstlane(e);
        int s0 = a[0], s1 = a[1];
        floatx2 f0 = fp8x2_dec_word<false>((unsigned)hin[(size_t)s0 * 64 + lane]);
        floatx2 f1 = fp8x2_dec_word<false>((unsigned)hin[(size_t)s1 * 64 + lane]);
        ax += f0.x; ay += f0.y;
        bx += f1.x; by += f1.y;
    }
    if (e < end) {
        int s0 = *(adj + __builtin_amdgcn_readfirstlane(e));
        floatx2 f = fp8x2_dec_word<false>((unsigned)hin[(size_t)s0 * 64 + lane]);
        ax += f.x; ay += f.y;
    }

    const float w = 1.0f / (float)(end - beg + 1);    // 1/(deg+1)
    float2 r;
    r.x = (ax + bx) * w;
    r.y = (ay + by) * w;
    hout[(size_t)node * 64 + lane] = r;
    if (tout) tout[(size_t)node * 64 + lane] = fp8x2_enc(r.x, r.y);
}

extern "C" void kernel_launch(void* const* d_in, const int* in_sizes, int n_in,
                              void* d_out, int out_size, void* d_ws, size_t ws_size,
                              hipStream_t stream) {
    const float* x = (const float*)d_in[0];
    const int* ei = (const int*)d_in[1];
    const int N = in_sizes[0] / 128;   // D = 128
    const int E = in_sizes[1] / 2;
    const int* src = ei;
    const int* dst = ei + E;
    float* out = (float*)d_out;
    const int K = (N + 511) >> BSHIFT; // buckets (196 for N=100000)

    // workspace carve-out (256B aligned)
    char* ws = (char*)d_ws;
    size_t off = 0;
    auto carve = [&](size_t bytes) {
        void* p = ws + off;
        off = (off + bytes + 255) & ~(size_t)255;
        return p;
    };
    unsigned* partial = (unsigned*)carve((size_t)NB1 * 256 * 4);
    unsigned* bcnt    = (unsigned*)carve(256 * 4);
    unsigned* bbase   = (unsigned*)carve(256 * 4);
    unsigned* gcur    = (unsigned*)carve(256 * 4);
    int*      offs    = (int*)carve(((size_t)N + 1) * 4);
    uint2*    pairs   = (uint2*)carve((size_t)E * 8);
    int*      adj     = (int*)carve((size_t)E * 4);
    unsigned short* tab0 = (unsigned short*)carve((size_t)N * 64 * 2);  // fp8 ping
    unsigned short* tab1 = (unsigned short*)carve((size_t)N * 64 * 2);  // fp8 pong

    k_hist<<<NB1, 256, 0, stream>>>(dst, E, partial);
    k_bscan<<<1, 256, 0, stream>>>(partial, K, bcnt, bbase, gcur, offs, N, E);
    k_split<<<(E + TILE - 1) / TILE, 256, 0, stream>>>(src, dst, E, gcur, pairs);
    k_csr<<<K, 512, 0, stream>>>(pairs, bcnt, bbase, adj, offs, N);

    const int n2 = N * 64;   // ushort / float2 elements per layer
    k_init<<<MIN((n2 + 255) / 256, 2048), 256, 0, stream>>>(
        (const float2*)x, (float2*)out, tab0, n2);

    const size_t layer_sz = (size_t)N * 128;
    unsigned short* tabs[2] = { tab0, tab1 };
    for (int l = 1; l <= 3; ++l) {
        float* hout = out + (size_t)l * layer_sz;
        unsigned short* tin = tabs[(l - 1) & 1];
        unsigned short* tnext = (l < 3) ? tabs[l & 1] : (unsigned short*)nullptr;
        k_layer<<<(N + 3) / 4, 256, 0, stream>>>(tin, (float2*)hout, tnext, adj, offs, N);
    }
}

// Round 9
// 181.647 us; speedup vs baseline: 1.6601x; 1.1314x over previous
//
#include <hip/hip_runtime.h>
#include <hip/hip_fp16.h>

#ifndef MIN
#define MIN(a,b) ((a)<(b)?(a):(b))
#endif

// Bucketing: bucket = dst >> BSHIFT, 256 nodes/bucket, K = ceil(N/256) <= 512.
#define BSHIFT 8
#define NBKT 512         // LDS bucket-array size (K=391 for N=100000)
#define NB1 256          // blocks in histogram pass
#define TILE 8192        // edges per B3 block (512 threads x 16)
#define B4CAP 6144       // LDS adj capacity per bucket (avg ~4092, max ~4500)

typedef float floatx2 __attribute__((ext_vector_type(2)));

#if defined(__has_builtin)
#if __has_builtin(__builtin_amdgcn_cvt_pk_f32_fp8) && __has_builtin(__builtin_amdgcn_cvt_pk_fp8_f32)
#define HW_FP8 1
#endif
#endif

// ---- fp8 e4m3 (OCP) pair decode/encode; HW path on gfx950 ----
// HI must be a compile-time constant for the builtin.
template <bool HI>
__device__ __forceinline__ floatx2 fp8x2_dec_word(unsigned w) {
#ifdef HW_FP8
    return __builtin_amdgcn_cvt_pk_f32_fp8((int)w, HI);
#else
    unsigned v = HI ? (w >> 16) : w;
    floatx2 r;
    unsigned b0 = v & 0xFFu, b1 = (v >> 8) & 0xFFu;
    float f0 = __uint_as_float(((b0 & 0x80u) << 24) | ((b0 & 0x7Fu) << 20));
    float f1 = __uint_as_float(((b1 & 0x80u) << 24) | ((b1 & 0x7Fu) << 20));
    r.x = f0 * 1.329227995784916e+36f;   // 2^120
    r.y = f1 * 1.329227995784916e+36f;
    return r;
#endif
}

__device__ __forceinline__ unsigned short fp8x2_enc(float x, float y) {
#ifdef HW_FP8
    int p = __builtin_amdgcn_cvt_pk_fp8_f32(x, y, 0, false);
    return (unsigned short)((unsigned)p & 0xFFFFu);
#else
    auto enc1 = [](float f) -> unsigned {
        float yv = f * 7.52316384526264e-37f;   // 2^-120
        unsigned u = __float_as_uint(yv);
        unsigned s = (u >> 24) & 0x80u;
        unsigned em = u & 0x7FFFFFFFu;
        unsigned keep = em >> 20;
        unsigned rem = em & 0xFFFFFu;
        keep += (rem > 0x80000u || (rem == 0x80000u && (keep & 1u))) ? 1u : 0u;
        if (keep > 0x7Fu) keep = 0x7Fu;
        return s | keep;
    };
    return (unsigned short)(enc1(x) | (enc1(y) << 8));
#endif
}

// nontemporal 8-byte store helper (float2 -> double bit-cast)
__device__ __forceinline__ void nt_store_f2(float2* p, float2 v) {
    union { double d; float2 f; } u;
    u.f = v;
    __builtin_nontemporal_store(u.d, (double*)p);
}

// ---------------- B1: per-block bucket histogram (LDS, no global atomics) ---
__global__ void __launch_bounds__(512) k_hist(const int* __restrict__ dst, int E,
                                              unsigned* __restrict__ partial) {
    __shared__ unsigned c[NBKT];
    int t = threadIdx.x;
    c[t] = 0;
    __syncthreads();
    int i = blockIdx.x * blockDim.x + t;
    int stride = gridDim.x * blockDim.x;
    for (; i < E; i += stride) atomicAdd(&c[((unsigned)dst[i]) >> BSHIFT], 1);
    __syncthreads();
    partial[blockIdx.x * NBKT + t] = c[t];
}

// ---------------- B2: reduce partials, scan -> bucket bases/cursors ---------
__global__ void __launch_bounds__(512) k_bscan(const unsigned* __restrict__ partial,
                                               int K, unsigned* __restrict__ bcnt,
                                               unsigned* __restrict__ bbase,
                                               unsigned* __restrict__ gcur,
                                               int* __restrict__ offs, int N, int E) {
    __shared__ unsigned sm[NBKT];
    int t = threadIdx.x;
    unsigned s = 0;
    if (t < K)
        for (int blk = 0; blk < NB1; ++blk) s += partial[blk * NBKT + t];
    sm[t] = (t < K) ? s : 0;
    __syncthreads();
    unsigned v = sm[t];
    for (int off = 1; off < NBKT; off <<= 1) {
        unsigned x = (t >= off) ? sm[t - off] : 0;
        __syncthreads();
        sm[t] += x;
        __syncthreads();
    }
    unsigned excl = sm[t] - v;
    if (t < K) {
        bcnt[t] = s;
        bbase[t] = excl;
        gcur[t] = excl;
    }
    if (t == 0) offs[N] = E;
}

// ---------------- B3: multisplit — tile-local sort by bucket, coalesced out -
// pk pack: bucket b (<512, 9 bits) << 13 | rank r (<8192, 13 bits).
__global__ void __launch_bounds__(512) k_split(const int* __restrict__ src,
                                               const int* __restrict__ dst, int E,
                                               unsigned* __restrict__ gcur,
                                               uint2* __restrict__ pairs) {
    __shared__ uint2 sp[TILE];            // 64 KB
    __shared__ unsigned cnt[NBKT], sscan[NBKT], gb[NBKT];
    int t = threadIdx.x;
    int base = blockIdx.x * TILE;
    cnt[t] = 0;
    __syncthreads();

    unsigned pk[TILE / 512];
    #pragma unroll
    for (int j = 0; j < TILE / 512; ++j) {
        int i = base + j * 512 + t;
        if (i < E) {
            unsigned b = ((unsigned)dst[i]) >> BSHIFT;
            unsigned r = atomicAdd(&cnt[b], 1);
            pk[j] = (b << 13) | r;
        } else {
            pk[j] = 0xFFFFFFFFu;
        }
    }
    __syncthreads();

    // exclusive scan of cnt -> sscan
    unsigned v = cnt[t];
    sscan[t] = v;
    __syncthreads();
    for (int off = 1; off < NBKT; off <<= 1) {
        unsigned x = (t >= off) ? sscan[t - off] : 0;
        __syncthreads();
        sscan[t] += x;
        __syncthreads();
    }
    sscan[t] -= v;
    __syncthreads();

    // local scatter into bucket-sorted order
    #pragma unroll
    for (int j = 0; j < TILE / 512; ++j) {
        if (pk[j] != 0xFFFFFFFFu) {
            int i = base + j * 512 + t;
            unsigned b = pk[j] >> 13, r = pk[j] & 8191u;
            sp[sscan[b] + r] = make_uint2((unsigned)src[i], (unsigned)dst[i]);
        }
    }
    __syncthreads();

    // one global claim per non-empty bucket
    unsigned n = cnt[t];
    gb[t] = n ? atomicAdd(&gcur[t], n) : 0u;
    __syncthreads();

    // coalesced write-out in bucket-run order
    int cntTile = MIN(TILE, E - base);
    #pragma unroll
    for (int j = 0; j < TILE / 512; ++j) {
        int p = j * 512 + t;
        if (p < cntTile) {
            uint2 e = sp[p];
            unsigned b = e.y >> BSHIFT;
            pairs[gb[b] + (unsigned)p - sscan[b]] = e;
        }
    }
}

// ---------------- B4: per-bucket CSR build fully in LDS, coalesced out ------
// 256 nodes/bucket, 512 threads, ~4092 edges avg -> 24 KB adjL, 2+ blocks/CU.
__global__ void __launch_bounds__(512) k_csr(const uint2* __restrict__ pairs,
                                             const unsigned* __restrict__ bcnt,
                                             const unsigned* __restrict__ bbase,
                                             int* __restrict__ adj,
                                             int* __restrict__ offs, int N) {
    __shared__ unsigned adjL[B4CAP];      // 24 KB
    __shared__ unsigned cnt[256], cnt2[256], sc[256];
    int t = threadIdx.x;
    int b = blockIdx.x;
    unsigned nb = bcnt[b];
    unsigned bb = bbase[b];
    if (t < 256) { cnt[t] = 0; cnt2[t] = 0; }
    __syncthreads();

    for (unsigned i = t; i < nb; i += 512)
        atomicAdd(&cnt[pairs[bb + i].y & 255u], 1);
    __syncthreads();

    // exclusive scan of per-node counts (256 entries, all threads hit barriers)
    unsigned v = 0;
    if (t < 256) { v = cnt[t]; sc[t] = v; }
    __syncthreads();
    for (int off = 1; off < 256; off <<= 1) {
        unsigned x = 0;
        if (t < 256 && t >= off) x = sc[t - off];
        __syncthreads();
        if (t < 256) sc[t] += x;
        __syncthreads();
    }
    if (t < 256) sc[t] -= v;
    __syncthreads();

    int node = (b << BSHIFT) + t;
    if (t < 256 && node < N) offs[node] = (int)(bb + sc[t]);

    if (nb <= B4CAP) {
        for (unsigned i = t; i < nb; i += 512) {
            uint2 e = pairs[bb + i];
            unsigned dl = e.y & 255u;
            unsigned pos = sc[dl] + atomicAdd(&cnt2[dl], 1);
            adjL[pos] = e.x;
        }
        __syncthreads();
        for (unsigned i = t; i < nb; i += 512) adj[bb + i] = (int)adjL[i];
    } else {  // statistical impossibility fallback, kept for safety
        for (unsigned i = t; i < nb; i += 512) {
            uint2 e = pairs[bb + i];
            unsigned dl = e.y & 255u;
            unsigned pos = sc[dl] + atomicAdd(&cnt2[dl], 1);
            adj[bb + pos] = (int)e.x;
        }
    }
}

// ---------------- layer 0: copy x -> out (f32, nt) and build fp8 table ------
__global__ void k_init(const float2* __restrict__ x2, float2* __restrict__ out2,
                       unsigned short* __restrict__ t8, int n2) {
    int i = blockIdx.x * blockDim.x + threadIdx.x;
    int stride = gridDim.x * blockDim.x;
    for (; i < n2; i += stride) {
        float2 v = x2[i];
        nt_store_f2(&out2[i], v);            // out0 never re-read: don't cache
        t8[i] = fp8x2_enc(v.x, v.y);         // table IS re-read: cache normally
    }
}

// ---------------- aggregation layer: one wave per node, fp8 row gathers -----
// One 128 B row per gather instruction (2 B/lane); adjacency through
// readfirstlane -> scalar s_load path. hout written nontemporal so the 51 MB
// f32 stream doesn't evict the 12.8 MB gather table from L2.
__global__ void __launch_bounds__(256) k_layer(
        const unsigned short* __restrict__ hin, float2* __restrict__ hout,
        unsigned short* __restrict__ tout, const int* __restrict__ adj,
        const int* __restrict__ offs, int N) {
    int wave = (blockIdx.x * blockDim.x + threadIdx.x) >> 6;
    int lane = threadIdx.x & 63;
    if (wave >= N) return;
    const int node = __builtin_amdgcn_readfirstlane(wave);
    const int beg = offs[node];
    const int end = offs[node + 1];

    floatx2 sf = fp8x2_dec_word<false>((unsigned)hin[(size_t)node * 64 + lane]);
    float ax = sf.x, ay = sf.y;          // self (self-loop)
    float bx = 0.f, by = 0.f;

    int e = beg;
    for (; e + 16 <= end; e += 16) {
        const int* __restrict__ a = adj + __builtin_amdgcn_readfirstlane(e);
        int s[16];
        #pragma unroll
        for (int j = 0; j < 16; ++j) s[j] = a[j];
        unsigned short v[16];
        #pragma unroll
        for (int j = 0; j < 16; ++j) v[j] = hin[(size_t)s[j] * 64 + lane];
        #pragma unroll
        for (int j = 0; j < 16; j += 2) {
            floatx2 f0 = fp8x2_dec_word<false>((unsigned)v[j]);
            floatx2 f1 = fp8x2_dec_word<false>((unsigned)v[j + 1]);
            ax += f0.x; ay += f0.y;
            bx += f1.x; by += f1.y;
        }
    }
    for (; e + 8 <= end; e += 8) {
        const int* __restrict__ a = adj + __builtin_amdgcn_readfirstlane(e);
        int s[8];
        #pragma unroll
        for (int j = 0; j < 8; ++j) s[j] = a[j];
        unsigned short v[8];
        #pragma unroll
        for (int j = 0; j < 8; ++j) v[j] = hin[(size_t)s[j] * 64 + lane];
        #pragma unroll
        for (int j = 0; j < 8; j += 2) {
            floatx2 f0 = fp8x2_dec_word<false>((unsigned)v[j]);
            floatx2 f1 = fp8x2_dec_word<false>((unsigned)v[j + 1]);
            ax += f0.x; ay += f0.y;
            bx += f1.x; by += f1.y;
        }
    }
    for (; e + 2 <= end; e += 2) {
        const int* __restrict__ a = adj + __builtin_amdgcn_readfirstlane(e);
        int s0 = a[0], s1 = a[1];
        floatx2 f0 = fp8x2_dec_word<false>((unsigned)hin[(size_t)s0 * 64 + lane]);
        floatx2 f1 = fp8x2_dec_word<false>((unsigned)hin[(size_t)s1 * 64 + lane]);
        ax += f0.x; ay += f0.y;
        bx += f1.x; by += f1.y;
    }
    if (e < end) {
        int s0 = *(adj + __builtin_amdgcn_readfirstlane(e));
        floatx2 f = fp8x2_dec_word<false>((unsigned)hin[(size_t)s0 * 64 + lane]);
        ax += f.x; ay += f.y;
    }

    const float w = 1.0f / (float)(end - beg + 1);    // 1/(deg+1)
    float2 r;
    r.x = (ax + bx) * w;
    r.y = (ay + by) * w;
    nt_store_f2(&hout[(size_t)node * 64 + lane], r);   // final output: bypass L2
    if (tout) tout[(size_t)node * 64 + lane] = fp8x2_enc(r.x, r.y);  // cached
}

extern "C" void kernel_launch(void* const* d_in, const int* in_sizes, int n_in,
                              void* d_out, int out_size, void* d_ws, size_t ws_size,
                              hipStream_t stream) {
    const float* x = (const float*)d_in[0];
    const int* ei = (const int*)d_in[1];
    const int N = in_sizes[0] / 128;   // D = 128
    const int E = in_sizes[1] / 2;
    const int* src = ei;
    const int* dst = ei + E;
    float* out = (float*)d_out;
    const int K = (N + 255) >> BSHIFT; // buckets (391 for N=100000)

    // workspace carve-out (256B aligned)
    char* ws = (char*)d_ws;
    size_t off = 0;
    auto carve = [&](size_t bytes) {
        void* p = ws + off;
        off = (off + bytes + 255) & ~(size_t)255;
        return p;
    };
    unsigned* partial = (unsigned*)carve((size_t)NB1 * NBKT * 4);
    unsigned* bcnt    = (unsigned*)carve(NBKT * 4);
    unsigned* bbase   = (unsigned*)carve(NBKT * 4);
    unsigned* gcur    = (unsigned*)carve(NBKT * 4);
    int*      offs    = (int*)carve(((size_t)N + 1) * 4);
    uint2*    pairs   = (uint2*)carve((size_t)E * 8);
    int*      adj     = (int*)carve((size_t)E * 4);
    unsigned short* tab0 = (unsigned short*)carve((size_t)N * 64 * 2);  // fp8 ping
    unsigned short* tab1 = (unsigned short*)carve((size_t)N * 64 * 2);  // fp8 pong

    k_hist<<<NB1, 512, 0, stream>>>(dst, E, partial);
    k_bscan<<<1, NBKT, 0, stream>>>(partial, K, bcnt, bbase, gcur, offs, N, E);
    k_split<<<(E + TILE - 1) / TILE, 512, 0, stream>>>(src, dst, E, gcur, pairs);
    k_csr<<<K, 512, 0, stream>>>(pairs, bcnt, bbase, adj, offs, N);

    const int n2 = N * 64;   // ushort / float2 elements per layer
    k_init<<<MIN((n2 + 255) / 256, 2048), 256, 0, stream>>>(
        (const float2*)x, (float2*)out, tab0, n2);

    const size_t layer_sz = (size_t)N * 128;
    unsigned short* tabs[2] = { tab0, tab1 };
    for (int l = 1; l <= 3; ++l) {
        float* hout = out + (size_t)l * layer_sz;
        unsigned short* tin = tabs[(l - 1) & 1];
        unsigned short* tnext = (l < 3) ? tabs[l & 1] : (unsigned short*)nullptr;
        k_layer<<<(N + 3) / 4, 256, 0, stream>>>(tin, (float2*)hout, tnext, adj, offs, N);
    }
}